// Round 11
// baseline (437.651 us; speedup 1.0000x reference)
//
#include <hip/hip_runtime.h>
#include <hip/hip_cooperative_groups.h>

namespace cg = cooperative_groups;

#define KINV  51.2f        // 256/5
#define KSTEP 0.01953125f  // 5/256 (exact in fp32)
#define TPW   7168
#define BCAP  256          // max edges per L-bin (avg 128)
#define DCAP  64           // max edges per dst node (avg 8)
#define NROW  11           // distinct t-rows
#define TSTR  40           // u-stride pad

typedef __attribute__((ext_vector_type(8))) __bf16 bf16x8;
typedef __attribute__((ext_vector_type(4))) float f32x4;
union FragU { uint4 u; bf16x8 v; };

__device__ __forceinline__ float sigmoidf_(float v) { return 1.f / (1.f + expf(-v)); }
__device__ __forceinline__ unsigned bf16r_(float x) { return (__float_as_uint(x) + 0x8000u) >> 16; }
__device__ __forceinline__ unsigned pk_(float lo, float hi) { return (bf16r_(hi) << 16) | bf16r_(lo); }

__device__ __forceinline__ f32x4 mfma_(bf16x8 a, bf16x8 b, f32x4 c) {
    return __builtin_amdgcn_mfma_f32_16x16x32_bf16(a, b, c, 0, 0, 0);
}

// One cooperative kernel: phase0 zero counters | phase1 table+scatter |
// phase2 MFMA fold | phase3 gather+node epilogue. Bodies identical to r9.
__global__ __launch_bounds__(256, 2)
void fused_kernel(const float* __restrict__ x, const float* __restrict__ ea,
                  const float* __restrict__ elen, const int* __restrict__ esrc,
                  const int* __restrict__ edst, const float* __restrict__ W1,
                  const float* __restrict__ W2, const float* __restrict__ Wss,
                  const float* __restrict__ Wsv, float* __restrict__ T,
                  float* __restrict__ msg, int* __restrict__ cntL,
                  int* __restrict__ cntD, int* __restrict__ sortedL,
                  int* __restrict__ sortedD, float* __restrict__ out,
                  int E, int N)
{
    cg::grid_group grid = cg::this_grid();
    __shared__ __align__(16) unsigned char SMEM[59392]; // BF 28672 + TB 28160 + EC 2560
    const int tid = threadIdx.x, bid = blockIdx.x;
    const int nb = gridDim.x;
    const float I3 = 0.5773502692f, I5 = 0.4472135955f, S2 = 0.7071067812f;
    const float I6 = 0.4082482905f, T6 = 0.8164965809f;
    const float A0 = 0.125f, A1 = 0.1767766953f;
    const float IM = 0.1767766953f;

    // ---- phase 0: zero cntL(256) + cntD(N), contiguous ----
    for (int gt = bid * 256 + tid; gt < 256 + N; gt += nb * 256) cntL[gt] = 0;
    __threadfence();
    grid.sync();

    // ---- phase 1: table (units 0..230) + padded-bin scatter (231..) ----
    {
        const int nscat = (E + 255) >> 8;
        for (int unit = bid; unit < 231 + nscat; unit += nb) {
            if (unit < 231) {
                float (*hk_s)[64] = (float (*)[64])SMEM;
                const int bx = unit % 7;
                const int k0 = (unit / 7) * 8;
                const int pw = bx * 1024 + tid * 4;
                __syncthreads();
#pragma unroll
                for (int q = 0; q < 2; ++q) {
                    int idx = tid + q * 256;
                    int kk = idx >> 6, c = idx & 63;
                    float L = (float)(k0 + kk) * KSTEP;
                    float d = 0.f;
#pragma unroll
                    for (int r = 0; r < 8; ++r) {
                        float dd = L - (float)r * (5.f / 7.f);
                        d += expf(-dd * dd * 0.98f) * W1[r * 64 + c];
                    }
                    d *= 0.3535533906f;
                    hk_s[kk][c] = d * sigmoidf_(d) * 0.125f;
                }
                __syncthreads();
                float4 acc[8];
#pragma unroll
                for (int q = 0; q < 8; ++q) acc[q] = make_float4(0.f, 0.f, 0.f, 0.f);
                for (int c = 0; c < 64; ++c) {
                    float4 w4 = *(const float4*)(W2 + (size_t)c * TPW + pw);
#pragma unroll
                    for (int q = 0; q < 8; ++q) {
                        float hv = hk_s[q][c];
                        acc[q].x = fmaf(hv, w4.x, acc[q].x);
                        acc[q].y = fmaf(hv, w4.y, acc[q].y);
                        acc[q].z = fmaf(hv, w4.z, acc[q].z);
                        acc[q].w = fmaf(hv, w4.w, acc[q].w);
                    }
                }
#pragma unroll
                for (int q = 0; q < 8; ++q) {
                    int k = k0 + q;
                    if (k < 257)
                        *(float4*)(T + (size_t)k * TPW + pw) = acc[q];
                }
            } else {
                int e = (unit - 231) * 256 + tid;
                if (e < E) {
                    float t = elen[e] * KINV;
                    int j = (int)t; j = j > 255 ? 255 : j;
                    int pos = atomicAdd(&cntL[j], 1);
                    if (pos < BCAP) sortedL[j * BCAP + pos] = e;
                    int dn = edst[e];
                    int pd = atomicAdd(&cntD[dn], 1);
                    if (pd < DCAP) sortedD[dn * DCAP + pd] = e;
                }
            }
        }
    }
    __threadfence();
    grid.sync();

    // ---- phase 2: MFMA fold (unit = interval*2 + half) ----
    {
        uint4* BF = (uint4*)SMEM;
        unsigned short* TB = (unsigned short*)(SMEM + 28672);
        float (*EC)[20] = (float (*)[20])(SMEM + 28672 + 28160);
        const int wv = tid >> 6, lane = tid & 63;
        const int sg = wv >> 1, wh = wv & 1;
        const int col = lane & 15, quad = lane >> 4;
        const int te = tid & 31, sub = tid >> 5;

        for (int unit = bid; unit < 512; unit += nb) {
            const int j = unit >> 1, half = unit & 1;
            __syncthreads();   // protect BF across units
            // stage B-fragments: Ta=T[j], D=T[j+1]-T[j], bf16-packed
            const float* Trow  = T + (size_t)j * TPW;
            const float* Trow2 = Trow + TPW;
            for (int i = tid; i < 896; i += 256) {
                int pl = i >> 7, rem = i & 127;
                int whs = rem >> 6, lane_s = rem & 63;
                int u0 = (lane_s >> 4) * 8, w = whs * 16 + (lane_s & 15);
                int basei = pl * 1024 + w;
                unsigned ta[4], dd[4];
#pragma unroll
                for (int q = 0; q < 4; ++q) {
                    float a0 = Trow[basei + (u0 + 2 * q) * 32];
                    float a1 = Trow[basei + (u0 + 2 * q + 1) * 32];
                    float b0 = Trow2[basei + (u0 + 2 * q) * 32];
                    float b1 = Trow2[basei + (u0 + 2 * q + 1) * 32];
                    ta[q] = pk_(a0, a1);
                    dd[q] = pk_(b0 - a0, b1 - a1);
                }
                BF[(pl * 4 + whs) * 64 + lane_s]     = make_uint4(ta[0], ta[1], ta[2], ta[3]);
                BF[(pl * 4 + 2 + whs) * 64 + lane_s] = make_uint4(dd[0], dd[1], dd[2], dd[3]);
            }

            const int cnt = min(cntL[j], BCAP);
            const int nchunk = (cnt + 31) >> 5;

            for (int ci = half; ci < nchunk; ci += 2) {
                const int base = ci << 5;
                const int cntE = min(32, cnt - base);
                __syncthreads();
                if (tid < 32 && tid < cntE) {
                    int e = sortedL[j * BCAP + base + tid];
                    float L = elen[e];
                    float t = L * KINV;
                    int jj = (int)t; jj = jj > 255 ? 255 : jj;
                    EC[tid][0] = t - (float)jj;
                    EC[tid][1] = __int_as_float(esrc[e]);
                    EC[tid][2] = __int_as_float(e);
                    const float* y = ea + (size_t)e * 9;
                    float y0 = y[0];
                    EC[tid][3] = y0;
                    EC[tid][4] = y0 * I3;
                    EC[tid][5] = y[1] * I3;
                    EC[tid][6] = y[2] * I3;
                    EC[tid][7] = y[3] * I3;
                    float a = y[4], b = y[5], c = y[6], d2 = y[7], ee = y[8];
                    EC[tid][8]  = (-c * I6 + ee * S2) * I5;
                    EC[tid][9]  = a * S2 * I5;
                    EC[tid][10] = d2 * S2 * I5;
                    EC[tid][11] = a * S2 * I5;
                    EC[tid][12] = (-c * I6 - ee * S2) * I5;
                    EC[tid][13] = b * S2 * I5;
                    EC[tid][14] = d2 * S2 * I5;
                    EC[tid][15] = b * S2 * I5;
                    EC[tid][16] = c * T6 * I5;
                }
                __syncthreads();

                // t-build: thread (te, sub) -> rows for edge te, u0..u0+3
                {
                    const int u0 = sub * 4;
                    const int esg = te >> 4, e16 = te & 15;
                    float rv[NROW][4];
                    if (te < cntE) {
                        int src = __float_as_int(EC[te][1]);
                        float y0 = EC[te][3], y0i = EC[te][4];
                        float y1i0 = EC[te][5], y1i1 = EC[te][6], y1i2 = EC[te][7];
                        float M0 = EC[te][8],  M1 = EC[te][9],  M2 = EC[te][10];
                        float M3 = EC[te][11], M4 = EC[te][12], M5 = EC[te][13];
                        float M6 = EC[te][14], M7 = EC[te][15], M8 = EC[te][16];
                        const float* xp = x + (size_t)src * 128;
                        float s4[4], vvv[12];
                        *(float4*)s4 = *(const float4*)(xp + u0);
                        *(float4*)(vvv)     = *(const float4*)(xp + 32 + 3 * u0);
                        *(float4*)(vvv + 4) = *(const float4*)(xp + 32 + 3 * u0 + 4);
                        *(float4*)(vvv + 8) = *(const float4*)(xp + 32 + 3 * u0 + 8);
#pragma unroll
                        for (int up = 0; up < 4; ++up) {
                            float s = s4[up];
                            float v0 = vvv[3 * up], v1 = vvv[3 * up + 1], v2 = vvv[3 * up + 2];
                            rv[0][up] = s * y0;
                            rv[1][up] = v0 * y1i0 + v1 * y1i1 + v2 * y1i2;
                            rv[2][up] = s * y1i0;
                            rv[3][up] = s * y1i1;
                            rv[4][up] = s * y1i2;
                            rv[5][up] = v0 * y0i;
                            rv[6][up] = v1 * y0i;
                            rv[7][up] = v2 * y0i;
                            rv[8][up]  = v0 * M0 + v1 * M3 + v2 * M6;
                            rv[9][up]  = v0 * M1 + v1 * M4 + v2 * M7;
                            rv[10][up] = v0 * M2 + v1 * M5 + v2 * M8;
                        }
                    } else {
#pragma unroll
                        for (int r = 0; r < NROW; ++r)
#pragma unroll
                            for (int up = 0; up < 4; ++up) rv[r][up] = 0.f;
                    }
#pragma unroll
                    for (int r = 0; r < NROW; ++r) {
                        unsigned lo2 = pk_(rv[r][0], rv[r][1]);
                        unsigned hi2 = pk_(rv[r][2], rv[r][3]);
                        *(uint2*)&TB[((esg * NROW + r) * 16 + e16) * TSTR + u0] = make_uint2(lo2, hi2);
                    }
                }
                __syncthreads();

                // MFMA phase
                f32x4 cS0 = {0,0,0,0}, cS1 = {0,0,0,0}, cG0 = {0,0,0,0}, cG1 = {0,0,0,0};
                f32x4 cV[3][2];
#pragma unroll
                for (int k = 0; k < 3; ++k) { cV[k][0] = (f32x4){0,0,0,0}; cV[k][1] = (f32x4){0,0,0,0}; }

                #define LOADA(r) ({ FragU fa_; fa_.u = *(const uint4*)&TB[((sg * NROW + (r)) * 16 + col) * TSTR + quad * 8]; fa_.v; })
                #define LOADB(p, tad) ({ FragU fb_; fb_.u = BF[((p) * 4 + (tad) * 2 + wh) * 64 + lane]; fb_.v; })

                bf16x8 a0 = LOADA(0), a1 = LOADA(1);
                cS0 = mfma_(a0, LOADB(0, 0), cS0); cS0 = mfma_(a1, LOADB(1, 0), cS0);
                cS1 = mfma_(a0, LOADB(0, 1), cS1); cS1 = mfma_(a1, LOADB(1, 1), cS1);
                cG0 = mfma_(a0, LOADB(2, 0), cG0); cG0 = mfma_(a1, LOADB(3, 0), cG0);
                cG1 = mfma_(a0, LOADB(2, 1), cG1); cG1 = mfma_(a1, LOADB(3, 1), cG1);
#pragma unroll
                for (int k = 0; k < 3; ++k) {
                    bf16x8 ak;
                    ak = LOADA(2 + k);
                    cV[k][0] = mfma_(ak, LOADB(4, 0), cV[k][0]);
                    cV[k][1] = mfma_(ak, LOADB(4, 1), cV[k][1]);
                    ak = LOADA(5 + k);
                    cV[k][0] = mfma_(ak, LOADB(5, 0), cV[k][0]);
                    cV[k][1] = mfma_(ak, LOADB(5, 1), cV[k][1]);
                    ak = LOADA(8 + k);
                    cV[k][0] = mfma_(ak, LOADB(6, 0), cV[k][0]);
                    cV[k][1] = mfma_(ak, LOADB(6, 1), cV[k][1]);
                }

                const int w = wh * 16 + col;
#pragma unroll
                for (int reg = 0; reg < 4; ++reg) {
                    int e = sg * 16 + quad * 4 + reg;
                    if (e < cntE) {
                        float f = EC[e][0];
                        int eid = __float_as_int(EC[e][2]);
                        float* mp = msg + (size_t)eid * 160;
                        mp[w]            = (cS0[reg] + f * cS1[reg]) * A0;
                        mp[32 + w]       = (cG0[reg] + f * cG1[reg]) * A0;
                        mp[64 + 3 * w]     = (cV[0][0][reg] + f * cV[0][1][reg]) * A1;
                        mp[64 + 3 * w + 1] = (cV[1][0][reg] + f * cV[1][1][reg]) * A1;
                        mp[64 + 3 * w + 2] = (cV[2][0][reg] + f * cV[2][1][reg]) * A1;
                    }
                }
                #undef LOADA
                #undef LOADB
            }
        }
    }
    __threadfence();
    grid.sync();

    // ---- phase 3: gather + node epilogue (8 nodes/unit) ----
    {
        float (*ms)[160] = (float (*)[160])SMEM;
        const int nunits = (N + 7) >> 3;
        for (int unit = bid; unit < nunits; unit += nb) {
            const int n0 = unit * 8;
            __syncthreads();   // protect ms across units
#pragma unroll
            for (int it = 0; it < 5; ++it) {
                int task = tid + it * 256;
                int nl = task / 160;
                int c = task - nl * 160;
                int n = n0 + nl;
                if (n < N) {
                    int cd = cntD[n];
                    int cc = cd < DCAP ? cd : DCAP;
                    float s = 0.f;
                    for (int i = 0; i < cc; ++i)
                        s += msg[(size_t)sortedD[n * DCAP + i] * 160 + c];
                    ms[nl][c] = s / fmaxf((float)cd, 1.f);
                }
            }
            __syncthreads();
#pragma unroll
            for (int it = 0; it < 2; ++it) {
                int task = tid + it * 256;
                int nl = task >> 6, c2 = task & 63;
                int n = n0 + nl;
                if (n >= N) continue;
                const float* m  = ms[nl];
                const float* xp = x + (size_t)n * 128;
                if (c2 < 32) {
                    int w = c2;
                    float mval = m[w];
                    float gs = mval * sigmoidf_(mval);
                    float dot = 0.f;
#pragma unroll 4
                    for (int u = 0; u < 32; ++u) dot += xp[u] * Wss[u * 32 + w];
                    float hs = gs + dot * IM;
                    out[(size_t)n * 64 + w] = sqrtf(hs * hs + 1e-12f);
                } else {
                    int w = c2 - 32;
                    float gate = sigmoidf_(m[32 + w]);
                    float g0 = m[64 + 3 * w + 0] * gate;
                    float g1 = m[64 + 3 * w + 1] * gate;
                    float g2 = m[64 + 3 * w + 2] * gate;
                    float d0 = 0.f, d1 = 0.f, d2 = 0.f;
#pragma unroll 4
                    for (int u = 0; u < 32; ++u) {
                        float wv = Wsv[u * 32 + w];
                        d0 += xp[32 + 3 * u + 0] * wv;
                        d1 += xp[32 + 3 * u + 1] * wv;
                        d2 += xp[32 + 3 * u + 2] * wv;
                    }
                    float h0 = g0 + d0 * IM, h1 = g1 + d1 * IM, h2 = g2 + d2 * IM;
                    out[(size_t)n * 64 + 32 + w] = sqrtf(h0 * h0 + h1 * h1 + h2 * h2 + 1e-12f);
                }
            }
        }
    }
}

extern "C" void kernel_launch(void* const* d_in, const int* in_sizes, int n_in,
                              void* d_out, int out_size, void* d_ws, size_t ws_size,
                              hipStream_t stream)
{
    const float* x    = (const float*)d_in[0];
    const float* ea   = (const float*)d_in[1];
    const float* elen = (const float*)d_in[2];
    const int*   esrc = (const int*)d_in[3];
    const int*   edst = (const int*)d_in[4];
    const float* W1   = (const float*)d_in[5];
    const float* W2   = (const float*)d_in[6];
    const float* Wss  = (const float*)d_in[7];
    const float* Wsv  = (const float*)d_in[8];
    float* out = (float*)d_out;

    int N = in_sizes[0] / 128;   // 4096
    int E = in_sizes[2];         // 32768

    float* T      = (float*)d_ws;                       // 257*TPW floats (7.4 MB)
    float* msg    = T + (size_t)257 * TPW;              // E*160 floats (21 MB)
    int*   cntL   = (int*)(msg + (size_t)E * 160);      // 256
    int*   cntD   = cntL + 256;                         // N
    int*   sortedL= cntD + N;                           // 256*BCAP
    int*   sortedD= sortedL + 256 * BCAP;               // N*DCAP

    void* args[] = { &x, &ea, &elen, &esrc, &edst, &W1, &W2, &Wss, &Wsv,
                     &T, &msg, &cntL, &cntD, &sortedL, &sortedD, &out, &E, &N };
    hipLaunchCooperativeKernel((const void*)fused_kernel, dim3(512), dim3(256),
                               args, 0, stream);
}

// Round 12
// 158.570 us; speedup vs baseline: 2.7600x; 2.7600x over previous
//
#include <hip/hip_runtime.h>

#define NIVL  256
#define KINV  51.2f        // 256/5
#define KSTEP 0.01953125f  // 5/256 (exact in fp32)
#define TPW   7168
#define BCAP  256          // max edges per L-bin (avg 128)
#define DCAP  64           // max edges per dst node (avg 8)
#define NROW  11           // distinct t-rows: t00,t11,t01[3],t10[3],t12[3]
#define TSTR  40           // u-stride (pad 32->40: 80B rows -> 16B-aligned b128)

typedef __attribute__((ext_vector_type(8))) __bf16 bf16x8;
typedef __attribute__((ext_vector_type(4))) float f32x4;
union FragU { uint4 u; bf16x8 v; };

__device__ __forceinline__ float sigmoidf_(float v) { return 1.f / (1.f + expf(-v)); }
__device__ __forceinline__ unsigned bf16r_(float x) { return (__float_as_uint(x) + 0x8000u) >> 16; }
__device__ __forceinline__ unsigned pk_(float lo, float hi) { return (bf16r_(hi) << 16) | bf16r_(lo); }

__device__ __forceinline__ f32x4 mfma_(bf16x8 a, bf16x8 b, f32x4 c) {
    return __builtin_amdgcn_mfma_f32_16x16x32_bf16(a, b, c, 0, 0, 0);
}

// ---- fat kernel: blocks 0..230 build T (257 knots), blocks 231.. scatter ----
__global__ __launch_bounds__(256)
void prep_kernel(const float* __restrict__ W1, const float* __restrict__ W2,
                 const float* __restrict__ elen, const int* __restrict__ edst,
                 float* __restrict__ T, int* __restrict__ cntL, int* __restrict__ cntD,
                 int* __restrict__ sortedL, int* __restrict__ sortedD, int E)
{
    const int tid = threadIdx.x;
    if (blockIdx.x < 231) {
        __shared__ float hk_s[8][64];
        const int bx = blockIdx.x % 7;
        const int k0 = (blockIdx.x / 7) * 8;
        const int pw = bx * 1024 + tid * 4;
#pragma unroll
        for (int q = 0; q < 2; ++q) {
            int idx = tid + q * 256;
            int kk = idx >> 6, c = idx & 63;
            float L = (float)(k0 + kk) * KSTEP;
            float d = 0.f;
#pragma unroll
            for (int r = 0; r < 8; ++r) {
                float dd = L - (float)r * (5.f / 7.f);
                d += expf(-dd * dd * 0.98f) * W1[r * 64 + c];
            }
            d *= 0.3535533906f;                      // 1/sqrt(8)
            hk_s[kk][c] = d * sigmoidf_(d) * 0.125f; // silu * 1/sqrt(64)
        }
        __syncthreads();
        float4 acc[8];
#pragma unroll
        for (int q = 0; q < 8; ++q) acc[q] = make_float4(0.f, 0.f, 0.f, 0.f);
        for (int c = 0; c < 64; ++c) {
            float4 w4 = *(const float4*)(W2 + (size_t)c * TPW + pw);
#pragma unroll
            for (int q = 0; q < 8; ++q) {
                float hv = hk_s[q][c];
                acc[q].x = fmaf(hv, w4.x, acc[q].x);
                acc[q].y = fmaf(hv, w4.y, acc[q].y);
                acc[q].z = fmaf(hv, w4.z, acc[q].z);
                acc[q].w = fmaf(hv, w4.w, acc[q].w);
            }
        }
#pragma unroll
        for (int q = 0; q < 8; ++q) {
            int k = k0 + q;
            if (k < 257)
                *(float4*)(T + (size_t)k * TPW + pw) = acc[q];
        }
    } else {
        int e = (blockIdx.x - 231) * 256 + tid;
        if (e < E) {
            float t = elen[e] * KINV;
            int j = (int)t; j = j > 255 ? 255 : j;
            int pos = atomicAdd(&cntL[j], 1);
            if (pos < BCAP) sortedL[j * BCAP + pos] = e;
            int d = edst[e];
            int pd = atomicAdd(&cntD[d], 1);
            if (pd < DCAP) sortedD[d * DCAP + pd] = e;
        }
    }
}

// ---- main fold: MFMA formulation ----
// Per interval j (2 blocks, halves): stage bf16 B-frags of Ta=T[j], D=T[j+1]-T[j]
// in frag-ready LDS layout; per 32-edge chunk build 11 bf16 t-rows/edge in LDS;
// 4 waves = (sg, wh); 26 MFMAs/wave into 10 f32x4 accs; epilogue Ta + f*D.
__global__ __launch_bounds__(256, 2)
void fold_kernel(const float* __restrict__ x, const float* __restrict__ ea,
                 const float* __restrict__ elen, const int* __restrict__ esrc,
                 const int* __restrict__ cntL, const int* __restrict__ sortedL,
                 const float* __restrict__ T, float* __restrict__ msg)
{
    const int j = blockIdx.x >> 1, half = blockIdx.x & 1;
    __shared__ uint4 BF[7 * 2 * 2 * 64];                       // 28672 B
    __shared__ __align__(16) unsigned short TB[2 * NROW * 16 * TSTR]; // 28160 B
    __shared__ float EC[32][20];
    const int tid = threadIdx.x;

    // ---- stage B-fragments: entry (p, wh, lane) -> Ta frag + D frag ----
    const float* Trow  = T + (size_t)j * TPW;
    const float* Trow2 = Trow + TPW;
    for (int i = tid; i < 896; i += 256) {
        int pl = i >> 7, rem = i & 127;
        int whs = rem >> 6, lane_s = rem & 63;
        int u0 = (lane_s >> 4) * 8, w = whs * 16 + (lane_s & 15);
        int basei = pl * 1024 + w;
        unsigned ta[4], dd[4];
#pragma unroll
        for (int q = 0; q < 4; ++q) {
            float a0 = Trow[basei + (u0 + 2 * q) * 32];
            float a1 = Trow[basei + (u0 + 2 * q + 1) * 32];
            float b0 = Trow2[basei + (u0 + 2 * q) * 32];
            float b1 = Trow2[basei + (u0 + 2 * q + 1) * 32];
            ta[q] = pk_(a0, a1);
            dd[q] = pk_(b0 - a0, b1 - a1);
        }
        BF[(pl * 4 + whs) * 64 + lane_s]     = make_uint4(ta[0], ta[1], ta[2], ta[3]);
        BF[(pl * 4 + 2 + whs) * 64 + lane_s] = make_uint4(dd[0], dd[1], dd[2], dd[3]);
    }

    const int cnt = min(cntL[j], BCAP);
    const int nchunk = (cnt + 31) >> 5;
    const int wv = tid >> 6, lane = tid & 63;
    const int sg = wv >> 1, wh = wv & 1;
    const int col = lane & 15, quad = lane >> 4;
    const int te = tid & 31, sub = tid >> 5;     // t-build mapping
    const float I3 = 0.5773502692f, I5 = 0.4472135955f, S2 = 0.7071067812f;
    const float I6 = 0.4082482905f, T6 = 0.8164965809f;
    const float A0 = 0.125f, A1 = 0.1767766953f;

    for (int ci = half; ci < nchunk; ci += 2) {
        const int base = ci << 5;
        const int cntE = min(32, cnt - base);
        __syncthreads();   // BF ready (iter 0); EC/TB free (later iters)
        if (tid < 32 && tid < cntE) {
            int e = sortedL[j * BCAP + base + tid];
            float L = elen[e];
            float t = L * KINV;
            int jj = (int)t; jj = jj > 255 ? 255 : jj;
            EC[tid][0] = t - (float)jj;
            EC[tid][1] = __int_as_float(esrc[e]);
            EC[tid][2] = __int_as_float(e);
            const float* y = ea + (size_t)e * 9;
            float y0 = y[0];
            EC[tid][3] = y0;
            EC[tid][4] = y0 * I3;
            EC[tid][5] = y[1] * I3;
            EC[tid][6] = y[2] * I3;
            EC[tid][7] = y[3] * I3;
            float a = y[4], b = y[5], c = y[6], d2 = y[7], ee = y[8];
            EC[tid][8]  = (-c * I6 + ee * S2) * I5;
            EC[tid][9]  = a * S2 * I5;
            EC[tid][10] = d2 * S2 * I5;
            EC[tid][11] = a * S2 * I5;
            EC[tid][12] = (-c * I6 - ee * S2) * I5;
            EC[tid][13] = b * S2 * I5;
            EC[tid][14] = d2 * S2 * I5;
            EC[tid][15] = b * S2 * I5;
            EC[tid][16] = c * T6 * I5;
        }
        __syncthreads();

        // ---- t-build: thread (te, sub) computes rows for edge te, u0..u0+3 ----
        {
            const int u0 = sub * 4;
            const int esg = te >> 4, e16 = te & 15;
            float rv[NROW][4];
            if (te < cntE) {
                int src = __float_as_int(EC[te][1]);
                float y0 = EC[te][3], y0i = EC[te][4];
                float y1i0 = EC[te][5], y1i1 = EC[te][6], y1i2 = EC[te][7];
                float M0 = EC[te][8],  M1 = EC[te][9],  M2 = EC[te][10];
                float M3 = EC[te][11], M4 = EC[te][12], M5 = EC[te][13];
                float M6 = EC[te][14], M7 = EC[te][15], M8 = EC[te][16];
                const float* xp = x + (size_t)src * 128;
                float s4[4], vv[12];
                *(float4*)s4 = *(const float4*)(xp + u0);
                *(float4*)(vv)     = *(const float4*)(xp + 32 + 3 * u0);
                *(float4*)(vv + 4) = *(const float4*)(xp + 32 + 3 * u0 + 4);
                *(float4*)(vv + 8) = *(const float4*)(xp + 32 + 3 * u0 + 8);
#pragma unroll
                for (int up = 0; up < 4; ++up) {
                    float s = s4[up];
                    float v0 = vv[3 * up], v1 = vv[3 * up + 1], v2 = vv[3 * up + 2];
                    rv[0][up] = s * y0;
                    rv[1][up] = v0 * y1i0 + v1 * y1i1 + v2 * y1i2;
                    rv[2][up] = s * y1i0;
                    rv[3][up] = s * y1i1;
                    rv[4][up] = s * y1i2;
                    rv[5][up] = v0 * y0i;
                    rv[6][up] = v1 * y0i;
                    rv[7][up] = v2 * y0i;
                    rv[8][up]  = v0 * M0 + v1 * M3 + v2 * M6;
                    rv[9][up]  = v0 * M1 + v1 * M4 + v2 * M7;
                    rv[10][up] = v0 * M2 + v1 * M5 + v2 * M8;
                }
            } else {
#pragma unroll
                for (int r = 0; r < NROW; ++r)
#pragma unroll
                    for (int up = 0; up < 4; ++up) rv[r][up] = 0.f;
            }
#pragma unroll
            for (int r = 0; r < NROW; ++r) {
                unsigned lo = pk_(rv[r][0], rv[r][1]);
                unsigned hi = pk_(rv[r][2], rv[r][3]);
                *(uint2*)&TB[((esg * NROW + r) * 16 + e16) * TSTR + u0] = make_uint2(lo, hi);
            }
        }
        __syncthreads();

        // ---- MFMA phase: wave (sg, wh) ----
        f32x4 cS0 = {0,0,0,0}, cS1 = {0,0,0,0}, cG0 = {0,0,0,0}, cG1 = {0,0,0,0};
        f32x4 cV[3][2];
#pragma unroll
        for (int k = 0; k < 3; ++k) { cV[k][0] = (f32x4){0,0,0,0}; cV[k][1] = (f32x4){0,0,0,0}; }

        #define LOADA(r) ({ FragU fa_; fa_.u = *(const uint4*)&TB[((sg * NROW + (r)) * 16 + col) * TSTR + quad * 8]; fa_.v; })
        #define LOADB(p, tad) ({ FragU fb_; fb_.u = BF[((p) * 4 + (tad) * 2 + wh) * 64 + lane]; fb_.v; })

        bf16x8 a0 = LOADA(0), a1 = LOADA(1);
        cS0 = mfma_(a0, LOADB(0, 0), cS0); cS0 = mfma_(a1, LOADB(1, 0), cS0);
        cS1 = mfma_(a0, LOADB(0, 1), cS1); cS1 = mfma_(a1, LOADB(1, 1), cS1);
        cG0 = mfma_(a0, LOADB(2, 0), cG0); cG0 = mfma_(a1, LOADB(3, 0), cG0);
        cG1 = mfma_(a0, LOADB(2, 1), cG1); cG1 = mfma_(a1, LOADB(3, 1), cG1);
#pragma unroll
        for (int k = 0; k < 3; ++k) {
            bf16x8 ak;
            ak = LOADA(2 + k);
            cV[k][0] = mfma_(ak, LOADB(4, 0), cV[k][0]);
            cV[k][1] = mfma_(ak, LOADB(4, 1), cV[k][1]);
            ak = LOADA(5 + k);
            cV[k][0] = mfma_(ak, LOADB(5, 0), cV[k][0]);
            cV[k][1] = mfma_(ak, LOADB(5, 1), cV[k][1]);
            ak = LOADA(8 + k);
            cV[k][0] = mfma_(ak, LOADB(6, 0), cV[k][0]);
            cV[k][1] = mfma_(ak, LOADB(6, 1), cV[k][1]);
        }

        // ---- epilogue: combine Ta + f*D, scale, store ----
        const int w = wh * 16 + col;
#pragma unroll
        for (int reg = 0; reg < 4; ++reg) {
            int e = sg * 16 + quad * 4 + reg;
            if (e < cntE) {
                float f = EC[e][0];
                int eid = __float_as_int(EC[e][2]);
                float* mp = msg + (size_t)eid * 160;
                mp[w]            = (cS0[reg] + f * cS1[reg]) * A0;
                mp[32 + w]       = (cG0[reg] + f * cG1[reg]) * A0;
                mp[64 + 3 * w]     = (cV[0][0][reg] + f * cV[0][1][reg]) * A1;
                mp[64 + 3 * w + 1] = (cV[1][0][reg] + f * cV[1][1][reg]) * A1;
                mp[64 + 3 * w + 2] = (cV[2][0][reg] + f * cV[2][1][reg]) * A1;
            }
        }
        #undef LOADA
        #undef LOADB
    }
}

// ---- fused gather + node epilogue: 8 nodes per block ----
__global__ __launch_bounds__(256)
void node_kernel(const float* __restrict__ x, const float* __restrict__ Wss,
                 const float* __restrict__ Wsv, const float* __restrict__ msg,
                 const int* __restrict__ sortedD, const int* __restrict__ cntD,
                 float* __restrict__ out, int N)
{
    __shared__ float ms[8][160];
    const int tid = threadIdx.x;
    const int n0 = blockIdx.x * 8;
    const float IM = 0.1767766953f;  // 1/sqrt(32)

#pragma unroll
    for (int it = 0; it < 5; ++it) {
        int task = tid + it * 256;
        int nl = task / 160;
        int c = task - nl * 160;
        int n = n0 + nl;
        if (n < N) {
            int cd = cntD[n];
            int cc = cd < DCAP ? cd : DCAP;
            float s = 0.f;
            for (int i = 0; i < cc; ++i)
                s += msg[(size_t)sortedD[n * DCAP + i] * 160 + c];
            ms[nl][c] = s / fmaxf((float)cd, 1.f);
        }
    }
    __syncthreads();

#pragma unroll
    for (int it = 0; it < 2; ++it) {
        int task = tid + it * 256;
        int nl = task >> 6, col = task & 63;
        int n = n0 + nl;
        if (n >= N) continue;
        const float* m  = ms[nl];
        const float* xp = x + (size_t)n * 128;
        if (col < 32) {
            int w = col;
            float mval = m[w];
            float gs = mval * sigmoidf_(mval);
            float dot = 0.f;
#pragma unroll 4
            for (int u = 0; u < 32; ++u) dot += xp[u] * Wss[u * 32 + w];
            float hs = gs + dot * IM;
            out[(size_t)n * 64 + w] = sqrtf(hs * hs + 1e-12f);
        } else {
            int w = col - 32;
            float gate = sigmoidf_(m[32 + w]);
            float g0 = m[64 + 3 * w + 0] * gate;
            float g1 = m[64 + 3 * w + 1] * gate;
            float g2 = m[64 + 3 * w + 2] * gate;
            float d0 = 0.f, d1 = 0.f, d2 = 0.f;
#pragma unroll 4
            for (int u = 0; u < 32; ++u) {
                float wv = Wsv[u * 32 + w];
                d0 += xp[32 + 3 * u + 0] * wv;
                d1 += xp[32 + 3 * u + 1] * wv;
                d2 += xp[32 + 3 * u + 2] * wv;
            }
            float h0 = g0 + d0 * IM, h1 = g1 + d1 * IM, h2 = g2 + d2 * IM;
            out[(size_t)n * 64 + 32 + w] = sqrtf(h0 * h0 + h1 * h1 + h2 * h2 + 1e-12f);
        }
    }
}

extern "C" void kernel_launch(void* const* d_in, const int* in_sizes, int n_in,
                              void* d_out, int out_size, void* d_ws, size_t ws_size,
                              hipStream_t stream)
{
    const float* x    = (const float*)d_in[0];
    const float* ea   = (const float*)d_in[1];
    const float* elen = (const float*)d_in[2];
    const int*   esrc = (const int*)d_in[3];
    const int*   edst = (const int*)d_in[4];
    const float* W1   = (const float*)d_in[5];
    const float* W2   = (const float*)d_in[6];
    const float* Wss  = (const float*)d_in[7];
    const float* Wsv  = (const float*)d_in[8];
    float* out = (float*)d_out;

    const int N = in_sizes[0] / 128;   // 4096
    const int E = in_sizes[2];         // 32768

    float* T      = (float*)d_ws;                       // 257*TPW floats (7.4 MB)
    float* msg    = T + (size_t)257 * TPW;              // E*160 floats (21 MB)
    int*   cntL   = (int*)(msg + (size_t)E * 160);      // 256
    int*   cntD   = cntL + 256;                         // N (4096)
    int*   sortedL= cntD + N;                           // 256*BCAP
    int*   sortedD= sortedL + 256 * BCAP;               // N*DCAP

    hipMemsetAsync(cntL, 0, (size_t)(256 + N) * sizeof(int), stream);

    prep_kernel<<<231 + (E + 255) / 256, 256, 0, stream>>>(W1, W2, elen, edst, T, cntL, cntD, sortedL, sortedD, E);
    fold_kernel<<<NIVL * 2, 256, 0, stream>>>(x, ea, elen, esrc, cntL, sortedL, T, msg);
    node_kernel<<<(N + 7) / 8, 256, 0, stream>>>(x, Wss, Wsv, msg, sortedD, cntD, out, N);
}